// Round 9
// baseline (873.093 us; speedup 1.0000x reference)
//
#include <hip/hip_runtime.h>
#include <hip/hip_bf16.h>

// loss = mean_n( logsumexp([pos_n, (online@queue)_n]/t) - pos_n/t )   (fwd: alpha mix = identity)
// v16 = v11 wave geometry (32x128 tile, 16x16x32, 512 thr, 4 waves/SIMD) with:
//   (a) 4 groups accumulated CONCURRENTLY (acc[4][2][8] = 256 AGPR): each B-fragment
//       ds_read feeds 32 MFMAs -> LDS B-traffic 2MB -> 512KB/block (pipe 20.5 -> 5.1 us,
//       MFMA 16.6 us becomes the binding pipe). Reg audit: ~380/wave x 4 waves <= 2048 OK.
//   (b) K-split double-buffered staging (2 x 32KB halves): stage K0 (5.1 us exposed),
//       issue K1 loads, RAW s_barrier with lgkmcnt(0) only (loads stay in flight, m201
//       pattern), compute all groups on K0 (~8.3 us MFMA-bound, hides K1 HBM), write K1,
//       barrier, compute K1. Staging exposure 10.2 -> ~5.1 us.
//   v13/v14/v15 post-mortems: A-pingpong null, 32x32 worse, setprio null -> the wins
//   left were the LDS-traffic floor and staging exposure; this attacks exactly those.

#define NROWS 1024
#define DDIM  256
#define KQ    65536
#define BN    128
#define NPART 512
#define LN2_F 0.69314718055994531f

typedef short  short8  __attribute__((ext_vector_type(8)));
typedef float  floatx4 __attribute__((ext_vector_type(4)));

__device__ __forceinline__ unsigned short f2bf(float f) {
    unsigned int u = __float_as_uint(f);
    u += 0x7FFFu + ((u >> 16) & 1u);   // RNE
    return (unsigned short)(u >> 16);
}

// DPP lane-permute (row-of-16 scope). quad_perm xor1=0xB1, xor2=0x4E,
// row_half_mirror=0x141 (pairs quads), row_mirror=0x140 (pairs octets).
#define DPPMOV(x, ctrl) \
    __uint_as_float(__builtin_amdgcn_mov_dpp(__float_as_uint(x), (ctrl), 0xF, 0xF, true))

__device__ __forceinline__ float dpp16_max(float x) {
    x = fmaxf(x, DPPMOV(x, 0xB1));
    x = fmaxf(x, DPPMOV(x, 0x4E));
    x = fmaxf(x, DPPMOV(x, 0x141));
    x = fmaxf(x, DPPMOV(x, 0x140));
    return x;   // all 16 lanes of the row-of-16 hold the max
}
__device__ __forceinline__ float dpp16_sum(float x) {
    x += DPPMOV(x, 0xB1);
    x += DPPMOV(x, 0x4E);
    x += DPPMOV(x, 0x141);
    x += DPPMOV(x, 0x140);
    return x;
}

// ---- A conversion: bf16(A/(t*ln2)); also zeroes the output accumulator ----
__global__ __launch_bounds__(256)
void conv_a(const float* __restrict__ A, const float* __restrict__ temp,
            unsigned short* __restrict__ Ab, float* __restrict__ out)
{
    if (blockIdx.x == 0 && threadIdx.x == 0) out[0] = 0.0f;
    const float s = 1.0f / (temp[0] * LN2_F);
    const int i = blockIdx.x * 256 + threadIdx.x;       // 65536 threads, one float4 each
    const floatx4 v = ((const floatx4*)A)[i];
    ushort4 w;
    w.x = f2bf(v.x * s); w.y = f2bf(v.y * s);
    w.z = f2bf(v.z * s); w.w = f2bf(v.w * s);
    ((ushort4*)Ab)[i] = w;
}

// ---- fused GEMM + online-softmax partials. 512 blocks x 512 thr; block = one 128-col stripe ----
__global__ __launch_bounds__(512, 4)
void gemm_softmax(const unsigned short* __restrict__ Ab,   // [1024][256] bf16, pre-scaled
                  const float* __restrict__ Q,             // [256][65536] fp32
                  float2* __restrict__ partials)           // [NPART][1024]  (part-major)
{
    // two K-half buffers: [128 n][128 k] bf16, 32 KB each, 16B-chunk XOR swizzled
    __shared__ __align__(16) unsigned short Bl[2][BN * 128];

    const int tid  = threadIdx.x;
    const int lane = tid & 63;
    const int wave = tid >> 6;          // 0..7 (32-row bands)
    const int l15  = lane & 15;
    const int quad = lane >> 4;
    const int nb   = blockIdx.x;        // 0..511
    const int nbase = nb * BN;

    // staging task (per K-half): 512 tasks = 1/thread. ny = 4-col group, ko = 8-k octet.
    const int ny = tid & 31;
    const int ko = tid >> 5;            // 0..15

    floatx4 v0[8], sv[8];

    // ---- stage K-half 0 ----
    #pragma unroll
    for (int j = 0; j < 8; ++j)
        v0[j] = __builtin_nontemporal_load(
                    (const floatx4*)(Q + (size_t)(ko * 8 + j) * KQ + nbase + ny * 4));
    #pragma unroll
    for (int i2 = 0; i2 < 4; ++i2) {
        const int n = ny * 4 + i2;
        const int phys = ko ^ (n & 15);          // 16B-chunk XOR swizzle (chunks 0..15)
        short8 w;
        #pragma unroll
        for (int j = 0; j < 8; ++j) w[j] = (short)f2bf(v0[j][i2]);
        *(short8*)&Bl[0][n * 128 + phys * 8] = w;
    }
    // ---- issue K-half 1 loads (stay in flight across the barrier) ----
    #pragma unroll
    for (int j = 0; j < 8; ++j)
        sv[j] = __builtin_nontemporal_load(
                    (const floatx4*)(Q + (size_t)(128 + ko * 8 + j) * KQ + nbase + ny * 4));

    asm volatile("s_waitcnt lgkmcnt(0)" ::: "memory");   // LDS writes visible; vmcnt NOT drained
    __builtin_amdgcn_s_barrier();                        // buf0 ready

    const unsigned short* apb = Ab + (size_t)(wave * 32 + l15) * DDIM + quad * 8;
    floatx4 acc[4][2][8] = {};                           // 4 groups concurrent: 256 acc regs

    // ---- K-half 0 compute: 4 supersteps, B-fragment shared by 4 groups (32 MFMA/read) ----
    #pragma unroll 1
    for (int s = 0; s < 4; ++s) {
        short8 af[4][2], bf[8];
        #pragma unroll
        for (int g = 0; g < 4; ++g)
            #pragma unroll
            for (int i = 0; i < 2; ++i)
                af[g][i] = *(const short8*)(apb + g * 65536 + i * 4096 + s * 32);
        {
            const int vb = l15 * 256 + (((4 * s + quad) ^ l15) * 16);
            #pragma unroll
            for (int j = 0; j < 8; ++j)
                bf[j] = *(const short8*)((const char*)&Bl[0][0] + vb + j * 4096);
        }
        __builtin_amdgcn_s_setprio(1);
        #pragma unroll
        for (int g = 0; g < 4; ++g)
            #pragma unroll
            for (int i = 0; i < 2; ++i)
                #pragma unroll
                for (int j = 0; j < 8; ++j)
                    acc[g][i][j] = __builtin_amdgcn_mfma_f32_16x16x32_bf16(af[g][i], bf[j], acc[g][i][j], 0, 0, 0);
        __builtin_amdgcn_s_setprio(0);
    }

    // ---- write K-half 1 (vmcnt wait on sv is ~free: HBM stream hid under compute) ----
    #pragma unroll
    for (int i2 = 0; i2 < 4; ++i2) {
        const int n = ny * 4 + i2;
        const int phys = ko ^ (n & 15);
        short8 w;
        #pragma unroll
        for (int j = 0; j < 8; ++j) w[j] = (short)f2bf(sv[j][i2]);
        *(short8*)&Bl[1][n * 128 + phys * 8] = w;
    }
    asm volatile("s_waitcnt lgkmcnt(0)" ::: "memory");
    __builtin_amdgcn_s_barrier();                        // buf1 ready

    // ---- K-half 1 compute ----
    #pragma unroll 1
    for (int s = 0; s < 4; ++s) {
        short8 af[4][2], bf[8];
        #pragma unroll
        for (int g = 0; g < 4; ++g)
            #pragma unroll
            for (int i = 0; i < 2; ++i)
                af[g][i] = *(const short8*)(apb + g * 65536 + i * 4096 + 128 + s * 32);
        {
            const int vb = l15 * 256 + (((4 * s + quad) ^ l15) * 16);
            #pragma unroll
            for (int j = 0; j < 8; ++j)
                bf[j] = *(const short8*)((const char*)&Bl[1][0] + vb + j * 4096);
        }
        __builtin_amdgcn_s_setprio(1);
        #pragma unroll
        for (int g = 0; g < 4; ++g)
            #pragma unroll
            for (int i = 0; i < 2; ++i)
                #pragma unroll
                for (int j = 0; j < 8; ++j)
                    acc[g][i][j] = __builtin_amdgcn_mfma_f32_16x16x32_bf16(af[g][i], bf[j], acc[g][i][j], 0, 0, 0);
        __builtin_amdgcn_s_setprio(0);
    }

    // ---- epilogue per group: base-2 logits. C layout: col=lane&15, row=quad*4+reg ----
    #pragma unroll
    for (int g = 0; g < 4; ++g) {
        const int rowbase = g * 256 + wave * 32;
        #pragma unroll
        for (int i = 0; i < 2; ++i) {
            float2 tmp[4];
            #pragma unroll
            for (int r = 0; r < 4; ++r) {
                float mx = acc[g][i][0][r];
                #pragma unroll
                for (int j = 1; j < 8; ++j) mx = fmaxf(mx, acc[g][i][j][r]);
                mx = dpp16_max(mx);
                float s2 = 0.f;
                #pragma unroll
                for (int j = 0; j < 8; ++j)
                    s2 += __builtin_amdgcn_exp2f(acc[g][i][j][r] - mx);
                s2 = dpp16_sum(s2);
                tmp[r] = make_float2(mx, s2);
            }
            if (l15 == 0) {
                // 4 quad-leader lanes cover 128 contiguous bytes
                const int row = rowbase + i * 16 + quad * 4;
                floatx4* dst = (floatx4*)(partials + (size_t)nb * NROWS + row);
                floatx4 w0 = {tmp[0].x, tmp[0].y, tmp[1].x, tmp[1].y};
                floatx4 w1 = {tmp[2].x, tmp[2].y, tmp[3].x, tmp[3].y};
                __builtin_nontemporal_store(w0, dst);
                __builtin_nontemporal_store(w1, dst + 1);
            }
        }
    }
}

// ---- combine partials per row + positive logit (computed inline) + atomic mean ----
// Grid: 64 blocks x 256 threads. Block owns 16 rows; 16 part-groups of 32 parts.
__global__ __launch_bounds__(256)
void finalize_rows(const float2* __restrict__ partials,   // [NPART][1024]
                   const float* __restrict__ online,
                   const float* __restrict__ mom,
                   const float* __restrict__ temp,
                   float* __restrict__ out)
{
    const int t = threadIdx.x;
    __shared__ float2 sm[16][17];
    __shared__ float sm_pos[16];

    // phase 1: positive-pair logit, 16 threads per row (rows r2 = t>>4)
    {
        const float s = 1.0f / (temp[0] * LN2_F);
        const int r2 = t >> 4, c2 = t & 15;
        const float* po = online + (size_t)(blockIdx.x * 16 + r2) * DDIM + c2 * 16;
        const float* pm = mom    + (size_t)(blockIdx.x * 16 + r2) * DDIM + c2 * 16;
        float d = 0.f;
        #pragma unroll
        for (int w = 0; w < 4; ++w) {
            const floatx4 a = *(const floatx4*)(po + w * 4);
            const floatx4 b = *(const floatx4*)(pm + w * 4);
            d += a.x * b.x + a.y * b.y + a.z * b.z + a.w * b.w;
        }
        d = dpp16_sum(d);
        if (c2 == 0) sm_pos[r2] = d * s;    // base-2-domain positive logit
    }

    // phase 2: combine negative partials; rl = row-in-block, grp = part group
    const int rl  = t & 15;
    const int grp = t >> 4;
    const int row = blockIdx.x * 16 + rl;

    float M = -3.0e38f, S = 0.f;
    #pragma unroll 1
    for (int pb = 0; pb < 32; pb += 8) {
        float2 v[8];
        #pragma unroll
        for (int j = 0; j < 8; ++j)
            v[j] = partials[(size_t)(grp * 32 + pb + j) * NROWS + row];
        #pragma unroll
        for (int j = 0; j < 8; ++j) {
            const float M2 = fmaxf(M, v[j].x);
            S = S * __builtin_amdgcn_exp2f(M - M2) + v[j].y * __builtin_amdgcn_exp2f(v[j].x - M2);
            M = M2;
        }
    }
    sm[grp][rl] = make_float2(M, S);
    __syncthreads();

    if (t < 64) {
        float val = 0.f;
        if (t < 16) {
            float Mm = -3.0e38f, Ss = 0.f;
            #pragma unroll
            for (int g2 = 0; g2 < 16; ++g2) {
                const float2 v = sm[g2][t];
                const float M2 = fmaxf(Mm, v.x);
                Ss = Ss * __builtin_amdgcn_exp2f(Mm - M2) + v.y * __builtin_amdgcn_exp2f(v.x - M2);
                Mm = M2;
            }
            const float p  = sm_pos[t];
            const float M2 = fmaxf(Mm, p);
            const float L  = Ss * __builtin_amdgcn_exp2f(Mm - M2) + __builtin_amdgcn_exp2f(p - M2);
            val = (M2 + __builtin_amdgcn_logf(L) - p) * LN2_F;   // back to natural log
        }
        val += __shfl_xor(val, 1, 64);
        val += __shfl_xor(val, 2, 64);
        val += __shfl_xor(val, 4, 64);
        val += __shfl_xor(val, 8, 64);
        val += __shfl_xor(val, 16, 64);
        val += __shfl_xor(val, 32, 64);
        if (t == 0) atomicAdd(out, val * (1.0f / (float)NROWS));
    }
}

extern "C" void kernel_launch(void* const* d_in, const int* in_sizes, int n_in,
                              void* d_out, int out_size, void* d_ws, size_t ws_size,
                              hipStream_t stream)
{
    const float* online = (const float*)d_in[0];   // [1024][256]
    const float* mom    = (const float*)d_in[1];   // [1024][256]
    const float* queue  = (const float*)d_in[2];   // [256][65536]
    const float* temp   = (const float*)d_in[3];   // [1]
    float* out = (float*)d_out;

    // ws: Ab bf16 [1024][256] (512 KB) | partials float2 [512][1024] (4 MB)
    char* ws = (char*)d_ws;
    unsigned short* Ab = (unsigned short*)ws;
    float2* partials   = (float2*)(ws + 524288);

    conv_a<<<256, 256, 0, stream>>>(online, temp, Ab, out);
    gemm_softmax<<<KQ / BN, 512, 0, stream>>>(Ab, queue, partials);
    finalize_rows<<<64, 256, 0, stream>>>(partials, online, mom, temp, out);
}

// Round 11
// 159.047 us; speedup vs baseline: 5.4895x; 5.4895x over previous
//
#include <hip/hip_runtime.h>
#include <hip/hip_bf16.h>

// loss = mean_n( logsumexp([pos_n, (online@queue)_n]/t) - pos_n/t )   (fwd: alpha mix = identity)
// v17 = v15 per-step shape VERBATIM (wave 32x128, acc[2][8]=64 AGPR, 16x16x32,
//   512 thr, 4 waves/SIMD, setprio around MFMA cluster) + K-split double-buffered
//   staging: stage K0 (32KB, ~5.1us exposed), issue K1 loads, s_barrier with ONLY
//   lgkmcnt(0) (K1 loads stay in flight), compute group0/K0 (hides K1 HBM stream),
//   write K1, barrier, group0/K1 + epilogue, then groups 1..3 full-K (both buffers
//   persist; barriers order write->read only). Staging exposure 10.2 -> ~5.1 us.
//   v16 post-mortem: acc[4][2][8]=256 regs spilled to scratch (FETCH 975MB, WRITE
//   1.9GB, 834us). Never exceed ~64 live acc regs in this structure.
//   (Round 10: resubmission — prior round was an infra failure, no bench data.)

#define NROWS 1024
#define DDIM  256
#define KQ    65536
#define BN    128
#define NPART 512
#define LN2_F 0.69314718055994531f

typedef short  short8  __attribute__((ext_vector_type(8)));
typedef float  floatx4 __attribute__((ext_vector_type(4)));

__device__ __forceinline__ unsigned short f2bf(float f) {
    unsigned int u = __float_as_uint(f);
    u += 0x7FFFu + ((u >> 16) & 1u);   // RNE
    return (unsigned short)(u >> 16);
}

// DPP lane-permute (row-of-16 scope). quad_perm xor1=0xB1, xor2=0x4E,
// row_half_mirror=0x141 (pairs quads), row_mirror=0x140 (pairs octets).
#define DPPMOV(x, ctrl) \
    __uint_as_float(__builtin_amdgcn_mov_dpp(__float_as_uint(x), (ctrl), 0xF, 0xF, true))

__device__ __forceinline__ float dpp16_max(float x) {
    x = fmaxf(x, DPPMOV(x, 0xB1));
    x = fmaxf(x, DPPMOV(x, 0x4E));
    x = fmaxf(x, DPPMOV(x, 0x141));
    x = fmaxf(x, DPPMOV(x, 0x140));
    return x;   // all 16 lanes of the row-of-16 hold the max
}
__device__ __forceinline__ float dpp16_sum(float x) {
    x += DPPMOV(x, 0xB1);
    x += DPPMOV(x, 0x4E);
    x += DPPMOV(x, 0x141);
    x += DPPMOV(x, 0x140);
    return x;
}

// ---- A conversion: bf16(A/(t*ln2)); also zeroes the output accumulator ----
__global__ __launch_bounds__(256)
void conv_a(const float* __restrict__ A, const float* __restrict__ temp,
            unsigned short* __restrict__ Ab, float* __restrict__ out)
{
    if (blockIdx.x == 0 && threadIdx.x == 0) out[0] = 0.0f;
    const float s = 1.0f / (temp[0] * LN2_F);
    const int i = blockIdx.x * 256 + threadIdx.x;       // 65536 threads, one float4 each
    const floatx4 v = ((const floatx4*)A)[i];
    ushort4 w;
    w.x = f2bf(v.x * s); w.y = f2bf(v.y * s);
    w.z = f2bf(v.z * s); w.w = f2bf(v.w * s);
    ((ushort4*)Ab)[i] = w;
}

// ---- fused GEMM + online-softmax partials. 512 blocks x 512 thr; block = one 128-col stripe ----
__global__ __launch_bounds__(512, 4)
void gemm_softmax(const unsigned short* __restrict__ Ab,   // [1024][256] bf16, pre-scaled
                  const float* __restrict__ Q,             // [256][65536] fp32
                  float2* __restrict__ partials)           // [NPART][1024]  (part-major)
{
    // two K-half buffers: [128 n][128 k] bf16, 32 KB each, 16B-chunk XOR swizzled
    __shared__ __align__(16) unsigned short Bl[2][BN * 128];

    const int tid  = threadIdx.x;
    const int lane = tid & 63;
    const int wave = tid >> 6;          // 0..7 (32-row bands)
    const int l15  = lane & 15;
    const int quad = lane >> 4;
    const int nb   = blockIdx.x;        // 0..511
    const int nbase = nb * BN;

    // staging task (per K-half): 512 tasks = 1/thread. ny = 4-col group, ko = 8-k octet.
    const int ny = tid & 31;
    const int ko = tid >> 5;            // 0..15

    // ---- stage K-half 0 (fp32 -> bf16 register transpose, XOR swizzle) ----
    {
        floatx4 v0[8];
        #pragma unroll
        for (int j = 0; j < 8; ++j)
            v0[j] = __builtin_nontemporal_load(
                        (const floatx4*)(Q + (size_t)(ko * 8 + j) * KQ + nbase + ny * 4));
        #pragma unroll
        for (int i2 = 0; i2 < 4; ++i2) {
            const int n = ny * 4 + i2;
            const int phys = ko ^ (n & 15);          // 16B-chunk XOR swizzle (chunks 0..15)
            short8 w;
            #pragma unroll
            for (int j = 0; j < 8; ++j) w[j] = (short)f2bf(v0[j][i2]);
            *(short8*)&Bl[0][n * 128 + phys * 8] = w;
        }
    }
    // ---- issue K-half 1 loads; they stay in flight across the barrier ----
    floatx4 sv[8];
    #pragma unroll
    for (int j = 0; j < 8; ++j)
        sv[j] = __builtin_nontemporal_load(
                    (const floatx4*)(Q + (size_t)(128 + ko * 8 + j) * KQ + nbase + ny * 4));

    asm volatile("s_waitcnt lgkmcnt(0)" ::: "memory");   // LDS writes visible; vmcnt NOT drained
    __builtin_amdgcn_s_barrier();                        // buf0 ready

    // one K-half (4 steps) of one group's accumulation; per-step shape == v11
    auto half_steps = [&](floatx4 (&acc)[2][8], const unsigned short* apb,
                          const char* blc, int af_off) {
        #pragma unroll 1
        for (int s = 0; s < 4; ++s) {
            short8 af[2], bf[8];
            #pragma unroll
            for (int i = 0; i < 2; ++i)
                af[i] = *(const short8*)(apb + i * 16 * DDIM + af_off + s * 32);
            {
                const int vb = l15 * 256 + (((4 * s + quad) ^ l15) * 16);
                #pragma unroll
                for (int j = 0; j < 8; ++j)
                    bf[j] = *(const short8*)(blc + vb + j * 4096);
            }
            __builtin_amdgcn_s_setprio(1);
            #pragma unroll
            for (int i = 0; i < 2; ++i)
                #pragma unroll
                for (int j = 0; j < 8; ++j)
                    acc[i][j] = __builtin_amdgcn_mfma_f32_16x16x32_bf16(af[i], bf[j], acc[i][j], 0, 0, 0);
            __builtin_amdgcn_s_setprio(0);
        }
    };

    // epilogue: base-2 logits. C layout: col(n)=lane&15, row(m)=quad*4+reg (verified).
    auto epilogue = [&](floatx4 (&acc)[2][8], int rowbase) {
        #pragma unroll
        for (int i = 0; i < 2; ++i) {
            float2 tmp[4];
            #pragma unroll
            for (int r = 0; r < 4; ++r) {
                float mx = acc[i][0][r];
                #pragma unroll
                for (int j = 1; j < 8; ++j) mx = fmaxf(mx, acc[i][j][r]);
                mx = dpp16_max(mx);
                float s2 = 0.f;
                #pragma unroll
                for (int j = 0; j < 8; ++j)
                    s2 += __builtin_amdgcn_exp2f(acc[i][j][r] - mx);
                s2 = dpp16_sum(s2);
                tmp[r] = make_float2(mx, s2);
            }
            if (l15 == 0) {
                const int row = rowbase + i * 16 + quad * 4;   // 4 quad-leaders: 128B contiguous
                floatx4* dst = (floatx4*)(partials + (size_t)nb * NROWS + row);
                floatx4 w0 = {tmp[0].x, tmp[0].y, tmp[1].x, tmp[1].y};
                floatx4 w1 = {tmp[2].x, tmp[2].y, tmp[3].x, tmp[3].y};
                __builtin_nontemporal_store(w0, dst);
                __builtin_nontemporal_store(w1, dst + 1);
            }
        }
    };

    // ---- group 0, K-half 0 (hides the K1 HBM stream) ----
    {
        const int rowbase = wave * 32;
        const unsigned short* apb = Ab + (size_t)(rowbase + l15) * DDIM + quad * 8;
        floatx4 acc[2][8] = {};
        half_steps(acc, apb, (const char*)&Bl[0][0], 0);

        // ---- write K-half 1 (compiler inserts the vmcnt wait on sv) ----
        #pragma unroll
        for (int i2 = 0; i2 < 4; ++i2) {
            const int n = ny * 4 + i2;
            const int phys = ko ^ (n & 15);
            short8 w;
            #pragma unroll
            for (int j = 0; j < 8; ++j) w[j] = (short)f2bf(sv[j][i2]);
            *(short8*)&Bl[1][n * 128 + phys * 8] = w;
        }
        asm volatile("s_waitcnt lgkmcnt(0)" ::: "memory");
        __builtin_amdgcn_s_barrier();                    // buf1 ready

        // ---- group 0, K-half 1 + epilogue ----
        half_steps(acc, apb, (const char*)&Bl[1][0], 128);
        epilogue(acc, rowbase);
    }

    // ---- groups 1..3, full K from the two persistent buffers ----
    #pragma unroll 1
    for (int g = 1; g < 4; ++g) {
        const int rowbase = g * 256 + wave * 32;
        const unsigned short* apb = Ab + (size_t)(rowbase + l15) * DDIM + quad * 8;
        floatx4 acc[2][8] = {};
        half_steps(acc, apb, (const char*)&Bl[0][0], 0);
        half_steps(acc, apb, (const char*)&Bl[1][0], 128);
        epilogue(acc, rowbase);
    }
}

// ---- combine partials per row + positive logit (computed inline) + atomic mean ----
// Grid: 64 blocks x 256 threads. Block owns 16 rows; 16 part-groups of 32 parts.
__global__ __launch_bounds__(256)
void finalize_rows(const float2* __restrict__ partials,   // [NPART][1024]
                   const float* __restrict__ online,
                   const float* __restrict__ mom,
                   const float* __restrict__ temp,
                   float* __restrict__ out)
{
    const int t = threadIdx.x;
    __shared__ float2 sm[16][17];
    __shared__ float sm_pos[16];

    // phase 1: positive-pair logit, 16 threads per row (rows r2 = t>>4)
    {
        const float s = 1.0f / (temp[0] * LN2_F);
        const int r2 = t >> 4, c2 = t & 15;
        const float* po = online + (size_t)(blockIdx.x * 16 + r2) * DDIM + c2 * 16;
        const float* pm = mom    + (size_t)(blockIdx.x * 16 + r2) * DDIM + c2 * 16;
        float d = 0.f;
        #pragma unroll
        for (int w = 0; w < 4; ++w) {
            const floatx4 a = *(const floatx4*)(po + w * 4);
            const floatx4 b = *(const floatx4*)(pm + w * 4);
            d += a.x * b.x + a.y * b.y + a.z * b.z + a.w * b.w;
        }
        d = dpp16_sum(d);
        if (c2 == 0) sm_pos[r2] = d * s;    // base-2-domain positive logit
    }

    // phase 2: combine negative partials; rl = row-in-block, grp = part group
    const int rl  = t & 15;
    const int grp = t >> 4;
    const int row = blockIdx.x * 16 + rl;

    float M = -3.0e38f, S = 0.f;
    #pragma unroll 1
    for (int pb = 0; pb < 32; pb += 8) {
        float2 v[8];
        #pragma unroll
        for (int j = 0; j < 8; ++j)
            v[j] = partials[(size_t)(grp * 32 + pb + j) * NROWS + row];
        #pragma unroll
        for (int j = 0; j < 8; ++j) {
            const float M2 = fmaxf(M, v[j].x);
            S = S * __builtin_amdgcn_exp2f(M - M2) + v[j].y * __builtin_amdgcn_exp2f(v[j].x - M2);
            M = M2;
        }
    }
    sm[grp][rl] = make_float2(M, S);
    __syncthreads();

    if (t < 64) {
        float val = 0.f;
        if (t < 16) {
            float Mm = -3.0e38f, Ss = 0.f;
            #pragma unroll
            for (int g2 = 0; g2 < 16; ++g2) {
                const float2 v = sm[g2][t];
                const float M2 = fmaxf(Mm, v.x);
                Ss = Ss * __builtin_amdgcn_exp2f(Mm - M2) + v.y * __builtin_amdgcn_exp2f(v.x - M2);
                Mm = M2;
            }
            const float p  = sm_pos[t];
            const float M2 = fmaxf(Mm, p);
            const float L  = Ss * __builtin_amdgcn_exp2f(Mm - M2) + __builtin_amdgcn_exp2f(p - M2);
            val = (M2 + __builtin_amdgcn_logf(L) - p) * LN2_F;   // back to natural log
        }
        val += __shfl_xor(val, 1, 64);
        val += __shfl_xor(val, 2, 64);
        val += __shfl_xor(val, 4, 64);
        val += __shfl_xor(val, 8, 64);
        val += __shfl_xor(val, 16, 64);
        val += __shfl_xor(val, 32, 64);
        if (t == 0) atomicAdd(out, val * (1.0f / (float)NROWS));
    }
}

extern "C" void kernel_launch(void* const* d_in, const int* in_sizes, int n_in,
                              void* d_out, int out_size, void* d_ws, size_t ws_size,
                              hipStream_t stream)
{
    const float* online = (const float*)d_in[0];   // [1024][256]
    const float* mom    = (const float*)d_in[1];   // [1024][256]
    const float* queue  = (const float*)d_in[2];   // [256][65536]
    const float* temp   = (const float*)d_in[3];   // [1]
    float* out = (float*)d_out;

    // ws: Ab bf16 [1024][256] (512 KB) | partials float2 [512][1024] (4 MB)
    char* ws = (char*)d_ws;
    unsigned short* Ab = (unsigned short*)ws;
    float2* partials   = (float2*)(ws + 524288);

    conv_a<<<256, 256, 0, stream>>>(online, temp, Ab, out);
    gemm_softmax<<<KQ / BN, 512, 0, stream>>>(Ab, queue, partials);
    finalize_rows<<<64, 256, 0, stream>>>(partials, online, mom, temp, out);
}